// Round 8
// baseline (409.773 us; speedup 1.0000x reference)
//
#include <hip/hip_runtime.h>
#include <stdint.h>

typedef __attribute__((ext_vector_type(4))) float f32x4;
typedef __attribute__((ext_vector_type(8))) __bf16 bf16x8;
typedef __attribute__((ext_vector_type(8))) unsigned short u16x8;
typedef __attribute__((ext_vector_type(4))) uint32_t u32x4;

#define GLOBAL_AS __attribute__((address_space(1)))
#define LDS_AS    __attribute__((address_space(3)))

// async global->LDS, 16B per lane; LDS dest = wave-uniform base + lane*16
__device__ __forceinline__ void lds_load16(const void* g, void* l) {
  __builtin_amdgcn_global_load_lds((const GLOBAL_AS uint32_t*)(uintptr_t)g,
                                   (LDS_AS uint32_t*)(uintptr_t)l, 16, 0, 0);
}

__device__ __forceinline__ unsigned short f2bf(float f) {
  uint32_t u = __builtin_bit_cast(uint32_t, f);
  u += 0x7fffu + ((u >> 16) & 1u);   // RNE
  return (unsigned short)(u >> 16);
}

__device__ __forceinline__ uint32_t pk_bf16(float a, float b) {
#if __has_builtin(__builtin_amdgcn_cvt_pk_bf16_f32)
  return __builtin_bit_cast(uint32_t, __builtin_amdgcn_cvt_pk_bf16_f32(a, b));
#else
  return (uint32_t)f2bf(a) | ((uint32_t)f2bf(b) << 16);
#endif
}

__device__ __forceinline__ float exp2f_fast(float x) {
#if __has_builtin(__builtin_amdgcn_exp2f)
  return __builtin_amdgcn_exp2f(x);          // raw v_exp_f32 (base-2)
#else
  return __expf(x * 0.6931471805599453f);
#endif
}

// pack two f32x4 (8 scores) into one bf16x8 A-fragment
__device__ __forceinline__ bf16x8 pack8(const f32x4 a, const f32x4 b) {
  u32x4 d;
  d.x = pk_bf16(a[0], a[1]);
  d.y = pk_bf16(a[2], a[3]);
  d.z = pk_bf16(b[0], b[1]);
  d.w = pk_bf16(b[2], b[3]);
  return __builtin_bit_cast(bf16x8, d);
}

// softmax scale folded with log2(e): exp(x/8) = exp2(x*0.125*1.442695)
#define QK_SCALE 0.18033688011112042f

// ---- cast: WEIGHTS ONLY now (Wq,Wk,Wv,Wo — 1024 blocks each).
// q/k/v fp32 are consumed directly by gemm_qkv via reg-staging.
__global__ void cast_all(const float* __restrict__ Wq, const float* __restrict__ Wk,
                         const float* __restrict__ Wv, const float* __restrict__ Wo,
                         unsigned short* __restrict__ dst) {
  const int bid = blockIdx.x;
  const int w = bid >> 10;
  const int rel = bid & 1023;
  const float* src = (w == 0) ? Wq : (w == 1) ? Wk : (w == 2) ? Wv : Wo;
  const size_t di = (size_t)bid * 1024 + threadIdx.x * 4;
  const size_t si = (size_t)rel * 1024 + threadIdx.x * 4;
  const float4 val = *(const float4*)(src + si);
  ushort4 o;
  o.x = f2bf(val.x); o.y = f2bf(val.y); o.z = f2bf(val.z); o.w = f2bf(val.w);
  *(ushort4*)(dst + di) = o;
}

// ---- fused Q/K/V^T projection GEMMs, v4 = R6's BK=64 XOR-swizzle structure
// (the best measured), with the fp32 operand staged via registers:
// float4 loads -> cvt_pk_bf16 -> ds_write_b128 directly at the swizzled
// position (write-side swizzle == read-side swizzle; rule #21 satisfied).
// gy=0: A=q(fp32) B=wq(bf16)  gy=1: A=k(fp32) B=wk(bf16)
// gy=2: A=wv(bf16) B=v(fp32)   — exactly one fp32 operand each.
__global__ __launch_bounds__(256, 2)
void gemm_qkv(const float* __restrict__ qf, const float* __restrict__ kf,
              const float* __restrict__ vf,
              const unsigned short* __restrict__ wq, const unsigned short* __restrict__ wk,
              const unsigned short* __restrict__ wv,
              const float* __restrict__ bq, const float* __restrict__ bk,
              const float* __restrict__ bv,
              unsigned short* __restrict__ Qh, unsigned short* __restrict__ Kh,
              unsigned short* __restrict__ Vt)
{
  __shared__ __align__(16) unsigned short As[128 * 64];
  __shared__ __align__(16) unsigned short Bs[128 * 64];

  const int gy = blockIdx.y, gx = blockIdx.x;
  const float* F             = (gy == 0) ? qf : (gy == 1) ? kf : vf;   // fp32 side
  const unsigned short* Wb   = (gy == 0) ? wq : (gy == 1) ? wk : wv;   // bf16 side
  const float* bias          = (gy == 0) ? bq : (gy == 1) ? bk : bv;

  int m0, n0, N;
  if (gy < 2) { m0 = (gx >> 3) * 128; n0 = (gx & 7) * 128; N = 1024; }
  else        { m0 = (gx & 7) * 128;  n0 = (gx >> 3) * 128; N = 8192; }
  const int K = 1024;

  // fp32 operand occupies A-rows (m) for gy<2, B-rows (n) for gy==2
  const int frow0 = (gy < 2) ? m0 : n0;
  const int wrow0 = (gy < 2) ? n0 : m0;
  unsigned short* Ts = (gy < 2) ? As : Bs;   // fp32 dest tile
  unsigned short* Us = (gy < 2) ? Bs : As;   // bf16 dest tile

  const int tid  = threadIdx.x;
  const int wave = tid >> 6;
  const int lane = tid & 63;
  const int wm = wave >> 1, wn = wave & 1;
  const int quad = lane >> 4, l15 = lane & 15;

  f32x4 acc[4][4];
#pragma unroll
  for (int i = 0; i < 4; ++i)
#pragma unroll
    for (int j = 0; j < 4; ++j) acc[i][j] = f32x4{0.f, 0.f, 0.f, 0.f};

  // bf16 staging via gload_lds: 8 rows/call, source col chunk inverse-swizzled
  const int sr8 = lane >> 3;
  const int scx = ((lane & 7) ^ (sr8 & 7)) * 8;
  const unsigned short* Wgb = Wb + (size_t)(wrow0 + wave * 8 + sr8) * K + scx;
  unsigned short* UsW = &Us[wave * 8 * 64];

  // fp32 staging: row fr (+t*32), LDS chunk p = lane&7 holds source chunk p^(r&7)
  const int fr = wave * 8 + sr8;
  const int pchunk = lane & 7;
  const int schunk = pchunk ^ (sr8 & 7);           // (t*32)&7 == 0, so r&7 == sr8&7
  const float* Fgb = F + (size_t)(frow0 + fr) * K + schunk * 8;
  unsigned short* TsW = &Ts[fr * 64 + pchunk * 8];

  // read column (per-l15 XOR unwinds the swizzle)
  const int colx0 = (quad * 8) ^ ((l15 & 7) * 8);
  const int colx1 = (32 + quad * 8) ^ ((l15 & 7) * 8);

  for (int k0 = 0; k0 < K; k0 += 64) {
    // bf16 side: 4 async gload_lds
#pragma unroll
    for (int t = 0; t < 4; ++t)
      lds_load16(Wgb + (size_t)(t * 32) * K + k0, UsW + t * 32 * 64);
    // fp32 side: reg-stage + convert + swizzled ds_write (2 t at a time for
    // load-latency overlap without register blowup)
#pragma unroll
    for (int th = 0; th < 2; ++th) {
      float4 v0a = *(const float4*)(Fgb + (size_t)((th * 2 + 0) * 32) * K + k0);
      float4 v1a = *(const float4*)(Fgb + (size_t)((th * 2 + 0) * 32) * K + k0 + 4);
      float4 v0b = *(const float4*)(Fgb + (size_t)((th * 2 + 1) * 32) * K + k0);
      float4 v1b = *(const float4*)(Fgb + (size_t)((th * 2 + 1) * 32) * K + k0 + 4);
      u32x4 da, db;
      da.x = pk_bf16(v0a.x, v0a.y); da.y = pk_bf16(v0a.z, v0a.w);
      da.z = pk_bf16(v1a.x, v1a.y); da.w = pk_bf16(v1a.z, v1a.w);
      db.x = pk_bf16(v0b.x, v0b.y); db.y = pk_bf16(v0b.z, v0b.w);
      db.z = pk_bf16(v1b.x, v1b.y); db.w = pk_bf16(v1b.z, v1b.w);
      *(u32x4*)(TsW + (th * 2 + 0) * 32 * 64) = da;
      *(u32x4*)(TsW + (th * 2 + 1) * 32 * 64) = db;
    }
    __syncthreads();

#pragma unroll
    for (int kd = 0; kd < 2; ++kd) {
      const int colx = kd ? colx1 : colx0;
      bf16x8 af[4], bfr[4];
#pragma unroll
      for (int i = 0; i < 4; ++i)
        af[i] = *(const bf16x8*)&As[(wm * 64 + i * 16 + l15) * 64 + colx];
#pragma unroll
      for (int j = 0; j < 4; ++j)
        bfr[j] = *(const bf16x8*)&Bs[(wn * 64 + j * 16 + l15) * 64 + colx];
#pragma unroll
      for (int i = 0; i < 4; ++i)
#pragma unroll
        for (int j = 0; j < 4; ++j)
          acc[i][j] = __builtin_amdgcn_mfma_f32_16x16x32_bf16(af[i], bfr[j], acc[i][j], 0, 0, 0);
    }
    __syncthreads();
  }

  if (gy < 2) {
    unsigned short* out = (gy == 0) ? Qh : Kh;
    const float scl = (gy == 0) ? QK_SCALE : 1.0f;
    float bj[4];
#pragma unroll
    for (int j = 0; j < 4; ++j) bj[j] = bias[n0 + wn * 64 + j * 16 + l15];
#pragma unroll
    for (int i = 0; i < 4; ++i) {
      const int mbase = m0 + wm * 64 + i * 16 + quad * 4;
#pragma unroll
      for (int j = 0; j < 4; ++j) {
        const int n = n0 + wn * 64 + j * 16 + l15;
#pragma unroll
        for (int r = 0; r < 4; ++r) {
          const int m = mbase + r;
          const float vv = (acc[i][j][r] + bj[j]) * scl;
          const size_t idx = ((((size_t)(m >> 11) * 16 + (n >> 6)) << 11) + (size_t)(m & 2047)) * 64 + (n & 63);
          out[idx] = f2bf(vv);
        }
      }
    }
  } else {
#pragma unroll
    for (int i = 0; i < 4; ++i) {
      const int mbase = m0 + wm * 64 + i * 16 + quad * 4;
      float bm[4];
#pragma unroll
      for (int r = 0; r < 4; ++r) bm[r] = bias[mbase + r];
#pragma unroll
      for (int j = 0; j < 4; ++j) {
        const int n = n0 + wn * 64 + j * 16 + l15;
#pragma unroll
        for (int r = 0; r < 4; ++r)
          Vt[(size_t)(mbase + r) * N + n] = f2bf(acc[i][j][r] + bm[r]);
      }
    }
  }
}

// ---- flash attention: R6's verified v7 (max-free softmax, MFMA row-sum,
// XCD swizzle, setprio), single-buffer — best measured variant.
__global__ __launch_bounds__(256, 2)
void flash_attn(const unsigned short* __restrict__ Qh,
                const unsigned short* __restrict__ Kh,
                const unsigned short* __restrict__ VtG,
                unsigned short* __restrict__ Xo)
{
  __shared__ __align__(16) unsigned short Ks[128 * 72];   // [k][d] pad 8; also initial Q staging
  __shared__ __align__(16) unsigned short Vs[64 * 136];   // [d][k] pad 8

  // XCD swizzle: 16 q-blocks sharing one (b,h)'s K/V land on one XCD.
  const int fid = blockIdx.x + (blockIdx.y << 4) + (blockIdx.z << 8);
  const int wid = ((fid & 7) << 7) + (fid >> 3);       // bijective, 1024 % 8 == 0
  const int qb = wid & 15, h = (wid >> 4) & 15, b = wid >> 8;

  const int tid = threadIdx.x, wave = tid >> 6, lane = tid & 63;
  const int quad = lane >> 4, l15 = lane & 15;

  const size_t bh = (((size_t)b * 16 + h) << 17);          // * S*DK
  const unsigned short* Qg = Qh + bh + ((size_t)qb << 13); // * 128*64
  const unsigned short* Kg = Kh + bh;
  const unsigned short* Vg = VtG + ((size_t)(h * 64)) * 8192 + (size_t)b * 2048;

  // ---- stage Q tile into Ks region (row stride 72), read frags, done with it
#pragma unroll
  for (int p = 0; p < 4; ++p) {
    const int c = tid + p * 256;                 // 16B chunk id, 0..1023
    u16x8 qv = *(const u16x8*)(Qg + c * 8);
    *(u16x8*)&Ks[(c >> 3) * 72 + (c & 7) * 8] = qv;
  }
  __syncthreads();
  bf16x8 aq[2][2];
#pragma unroll
  for (int i = 0; i < 2; ++i)
#pragma unroll
    for (int d = 0; d < 2; ++d)
      aq[i][d] = *(const bf16x8*)&Ks[(wave * 32 + i * 16 + l15) * 72 + d * 32 + quad * 8];

  f32x4 oacc[2][4];
  f32x4 lacc[2];
#pragma unroll
  for (int i = 0; i < 2; ++i) {
#pragma unroll
    for (int jd = 0; jd < 4; ++jd) oacc[i][jd] = f32x4{0.f, 0.f, 0.f, 0.f};
    lacc[i] = f32x4{0.f, 0.f, 0.f, 0.f};
  }

  // constant all-ones bf16 B-fragment for the row-sum MFMA
  const uint32_t one2 = 0x3F803F80u;
  const u32x4 onesU{one2, one2, one2, one2};
  const bf16x8 onesB = __builtin_bit_cast(bf16x8, onesU);

  // pi5(rho(l15)): LDS base row for the permuted A-row read
  const int rb = (l15 >> 3) * 16 + ((l15 >> 2) & 1) * 4 + (l15 & 3);

  // software-pipelined K/V tile loads (prologue)
  u16x8 kreg[4], vreg[4];
#pragma unroll
  for (int p = 0; p < 4; ++p) {
    const int c = tid + p * 256;
    kreg[p] = *(const u16x8*)(Kg + c * 8);
    vreg[p] = *(const u16x8*)(Vg + (size_t)(c >> 4) * 8192 + (c & 15) * 8);
  }

  for (int kb = 0; kb < 16; ++kb) {
    __syncthreads();   // all waves done reading previous Ks/Vs (and Q staging at kb=0)
#pragma unroll
    for (int p = 0; p < 4; ++p) {
      const int c = tid + p * 256;
      const int kr = c >> 3;
      const int krp = (kr & ~12) | ((kr & 4) << 1) | ((kr & 8) >> 1);  // pi5: swap bits 2,3
      *(u16x8*)&Ks[krp * 72 + (c & 7) * 8] = kreg[p];
      *(u16x8*)&Vs[(c >> 4) * 136 + (c & 15) * 8] = vreg[p];
    }
    __syncthreads();

    // two 64-k halves; runtime loop (unroll 1) keeps per-half regs from merging
#pragma unroll 1
    for (int hh = 0; hh < 2; ++hh) {
      f32x4 s[2][4];
#pragma unroll
      for (int i = 0; i < 2; ++i)
#pragma unroll
        for (int j = 0; j < 4; ++j) s[i][j] = f32x4{0.f, 0.f, 0.f, 0.f};
      __builtin_amdgcn_s_setprio(1);
#pragma unroll
      for (int d = 0; d < 2; ++d)
#pragma unroll
        for (int j = 0; j < 4; ++j) {
          const int kk = j >> 1, p2 = j & 1;
          bf16x8 kf = *(const bf16x8*)&Ks[(hh * 64 + kk * 32 + p2 * 8 + rb) * 72 + d * 32 + quad * 8];
#pragma unroll
          for (int i = 0; i < 2; ++i)
            s[i][j] = __builtin_amdgcn_mfma_f32_16x16x32_bf16(kf, aq[i][d], s[i][j], 0, 0, 0);
        }
      __builtin_amdgcn_s_setprio(0);

      // max-free softmax: e = exp2(s) directly (v6 rationale)
#pragma unroll
      for (int i = 0; i < 2; ++i)
#pragma unroll
        for (int j = 0; j < 4; ++j)
#pragma unroll
          for (int r = 0; r < 4; ++r)
            s[i][j][r] = exp2f_fast(s[i][j][r]);

      // pack P -> bf16 A-frags (score regs die here)
      bf16x8 ap[2][2];
#pragma unroll
      for (int i = 0; i < 2; ++i)
#pragma unroll
        for (int kk = 0; kk < 2; ++kk)
          ap[i][kk] = pack8(s[i][2 * kk], s[i][2 * kk + 1]);

      // split prefetch: K after half 0, V after half 1 (16 regs each)
      if (kb < 15) {
        if (hh == 0) {
          const size_t ko = ((size_t)(kb + 1) << 13);
#pragma unroll
          for (int p = 0; p < 4; ++p) {
            const int c = tid + p * 256;
            kreg[p] = *(const u16x8*)(Kg + ko + c * 8);
          }
        } else {
#pragma unroll
          for (int p = 0; p < 4; ++p) {
            const int c = tid + p * 256;
            vreg[p] = *(const u16x8*)(Vg + (size_t)(c >> 4) * 8192 + (kb + 1) * 128 + (c & 15) * 8);
          }
        }
      }

      // l += P x ones and O += P V on the MFMA pipe
      __builtin_amdgcn_s_setprio(1);
#pragma unroll
      for (int i = 0; i < 2; ++i)
#pragma unroll
        for (int kk = 0; kk < 2; ++kk)
          lacc[i] = __builtin_amdgcn_mfma_f32_16x16x32_bf16(ap[i][kk], onesB, lacc[i], 0, 0, 0);
#pragma unroll
      for (int kk = 0; kk < 2; ++kk) {
#pragma unroll
        for (int jd = 0; jd < 4; ++jd) {
          bf16x8 bv = *(const bf16x8*)&Vs[(jd * 16 + l15) * 136 + (hh * 2 + kk) * 32 + quad * 8];
#pragma unroll
          for (int i = 0; i < 2; ++i)
            oacc[i][jd] = __builtin_amdgcn_mfma_f32_16x16x32_bf16(ap[i][kk], bv, oacc[i][jd], 0, 0, 0);
        }
      }
      __builtin_amdgcn_s_setprio(0);
    }
  }

  // epilogue: O / l, store bf16 to [B,S,H*DK]; lacc rows == oacc rows.
#pragma unroll
  for (int i = 0; i < 2; ++i)
#pragma unroll
    for (int r = 0; r < 4; ++r) {
      const float inv = 1.f / lacc[i][r];
      const int srow = qb * 128 + wave * 32 + i * 16 + quad * 4 + r;
      const size_t obase = (((size_t)b << 11) + srow) * 1024 + (h << 6);
#pragma unroll
      for (int jd = 0; jd < 4; ++jd)
        Xo[obase + jd * 16 + l15] = f2bf(oacc[i][jd][r] * inv);
    }
}

// ---- output projection: R6's BK=64 XOR-swizzle version (best measured).
__global__ __launch_bounds__(256, 2)
void gemm_out(const unsigned short* __restrict__ A,
              const unsigned short* __restrict__ Bw,
              const float* __restrict__ bias,
              float* __restrict__ Cout)
{
  __shared__ __align__(16) unsigned short As[128 * 64];
  __shared__ __align__(16) unsigned short Bs[128 * 64];

  const int tid  = threadIdx.x;
  const int wave = tid >> 6;
  const int lane = tid & 63;
  const int wm = wave >> 1, wn = wave & 1;
  const int quad = lane >> 4, l15 = lane & 15;
  const int m0 = blockIdx.y * 128;
  const int n0 = blockIdx.x * 128;
  const int K = 1024, N = 1024;

  f32x4 acc[4][4];
#pragma unroll
  for (int i = 0; i < 4; ++i)
#pragma unroll
    for (int j = 0; j < 4; ++j) acc[i][j] = f32x4{0.f, 0.f, 0.f, 0.f};

  const int sr8 = lane >> 3;
  const int scx = ((lane & 7) ^ (sr8 & 7)) * 8;
  const unsigned short* Agb = A  + (size_t)(m0 + wave * 8 + sr8) * K + scx;
  const unsigned short* Bgb = Bw + (size_t)(n0 + wave * 8 + sr8) * K + scx;
  unsigned short* AsW = &As[wave * 8 * 64];
  unsigned short* BsW = &Bs[wave * 8 * 64];

  const int colx0 = (quad * 8) ^ ((l15 & 7) * 8);
  const int colx1 = (32 + quad * 8) ^ ((l15 & 7) * 8);

  for (int k0 = 0; k0 < K; k0 += 64) {
#pragma unroll
    for (int t = 0; t < 4; ++t) {
      lds_load16(Agb + (size_t)(t * 32) * K + k0, AsW + t * 32 * 64);
      lds_load16(Bgb + (size_t)(t * 32) * K + k0, BsW + t * 32 * 64);
    }
    __syncthreads();

#pragma unroll
    for (int kd = 0; kd < 2; ++kd) {
      const int colx = kd ? colx1 : colx0;
      bf16x8 af[4], bfr[4];
#pragma unroll
      for (int i = 0; i < 4; ++i)
        af[i] = *(const bf16x8*)&As[(wm * 64 + i * 16 + l15) * 64 + colx];
#pragma unroll
      for (int j = 0; j < 4; ++j)
        bfr[j] = *(const bf16x8*)&Bs[(wn * 64 + j * 16 + l15) * 64 + colx];
#pragma unroll
      for (int i = 0; i < 4; ++i)
#pragma unroll
        for (int j = 0; j < 4; ++j)
          acc[i][j] = __builtin_amdgcn_mfma_f32_16x16x32_bf16(af[i], bfr[j], acc[i][j], 0, 0, 0);
    }
    __syncthreads();
  }

  float bj[4];
#pragma unroll
  for (int j = 0; j < 4; ++j) bj[j] = bias[n0 + wn * 64 + j * 16 + l15];

#pragma unroll
  for (int i = 0; i < 4; ++i) {
    const int mbase = m0 + wm * 64 + i * 16 + quad * 4;
#pragma unroll
    for (int j = 0; j < 4; ++j) {
      const int n = n0 + wn * 64 + j * 16 + l15;
#pragma unroll
      for (int r = 0; r < 4; ++r)
        Cout[(size_t)(mbase + r) * N + n] = acc[i][j][r] + bj[j];
    }
  }
}

extern "C" void kernel_launch(void* const* d_in, const int* in_sizes, int n_in,
                              void* d_out, int out_size, void* d_ws, size_t ws_size,
                              hipStream_t stream) {
  const float* q  = (const float*)d_in[0];
  const float* k  = (const float*)d_in[1];
  const float* v  = (const float*)d_in[2];
  const float* Wq = (const float*)d_in[3];
  const float* bq = (const float*)d_in[4];
  const float* Wk = (const float*)d_in[5];
  const float* bk = (const float*)d_in[6];
  const float* Wv = (const float*)d_in[7];
  const float* bv = (const float*)d_in[8];
  const float* Wo = (const float*)d_in[9];
  const float* bo = (const float*)d_in[10];

  const int B = 4, S = 2048, D = 1024, H = 16;
  const size_t NX = (size_t)B * S * D;   // 8388608
  const size_t NW = (size_t)D * D;       // 1048576

  unsigned short* xq = (unsigned short*)d_ws;   // (unused now, kept for layout)
  unsigned short* xk = xq + NX;                 // (unused)
  unsigned short* xv = xk + NX;                 // (unused)
  unsigned short* wq = xv + NX;
  unsigned short* wk = wq + NW;
  unsigned short* wv = wk + NW;
  unsigned short* wo = wv + NW;
  unsigned short* Qh = wo + NW;   // [B,H,S,DK]
  unsigned short* Kh = Qh + NX;   // [B,H,S,DK]
  unsigned short* Vt = Kh + NX;   // [D][B*S] = V^T
  unsigned short* xo = Vt + NX;   // [B,S,D] attention output, bf16

  // weights-only cast (4 x 1024 blocks); q/k/v consumed as fp32 by gemm_qkv
  cast_all<<<4096, 256, 0, stream>>>(Wq, Wk, Wv, Wo, wq);

  gemm_qkv<<<dim3(512, 3), 256, 0, stream>>>(q, k, v, wq, wk, wv, bq, bk, bv, Qh, Kh, Vt);

  flash_attn<<<dim3(S / 128, H, B), 256, 0, stream>>>(Qh, Kh, Vt, xo);

  gemm_out<<<dim3(D / 128, (B * S) / 128), 256, 0, stream>>>(xo, wo, bo, (float*)d_out);
}

// Round 9
// 345.171 us; speedup vs baseline: 1.1872x; 1.1872x over previous
//
#include <hip/hip_runtime.h>
#include <stdint.h>

typedef __attribute__((ext_vector_type(4))) float f32x4;
typedef __attribute__((ext_vector_type(8))) __bf16 bf16x8;
typedef __attribute__((ext_vector_type(8))) unsigned short u16x8;
typedef __attribute__((ext_vector_type(4))) uint32_t u32x4;

#define GLOBAL_AS __attribute__((address_space(1)))
#define LDS_AS    __attribute__((address_space(3)))

// async global->LDS, 16B per lane; LDS dest = wave-uniform base + lane*16
__device__ __forceinline__ void lds_load16(const void* g, void* l) {
  __builtin_amdgcn_global_load_lds((const GLOBAL_AS uint32_t*)(uintptr_t)g,
                                   (LDS_AS uint32_t*)(uintptr_t)l, 16, 0, 0);
}

__device__ __forceinline__ unsigned short f2bf(float f) {
  uint32_t u = __builtin_bit_cast(uint32_t, f);
  u += 0x7fffu + ((u >> 16) & 1u);   // RNE
  return (unsigned short)(u >> 16);
}

__device__ __forceinline__ uint32_t pk_bf16(float a, float b) {
#if __has_builtin(__builtin_amdgcn_cvt_pk_bf16_f32)
  return __builtin_bit_cast(uint32_t, __builtin_amdgcn_cvt_pk_bf16_f32(a, b));
#else
  return (uint32_t)f2bf(a) | ((uint32_t)f2bf(b) << 16);
#endif
}

__device__ __forceinline__ float exp2f_fast(float x) {
#if __has_builtin(__builtin_amdgcn_exp2f)
  return __builtin_amdgcn_exp2f(x);          // raw v_exp_f32 (base-2)
#else
  return __expf(x * 0.6931471805599453f);
#endif
}

// pack two f32x4 (8 scores) into one bf16x8 A-fragment
__device__ __forceinline__ bf16x8 pack8(const f32x4 a, const f32x4 b) {
  u32x4 d;
  d.x = pk_bf16(a[0], a[1]);
  d.y = pk_bf16(a[2], a[3]);
  d.z = pk_bf16(b[0], b[1]);
  d.w = pk_bf16(b[2], b[3]);
  return __builtin_bit_cast(bf16x8, d);
}

// softmax scale folded with log2(e): exp(x/8) = exp2(x*0.125*1.442695)
#define QK_SCALE 0.18033688011112042f

// ---- fused cast: q,k,v (8192 blocks each) then Wq,Wk,Wv,Wo (1024 each).
__global__ void cast_all(const float* __restrict__ q, const float* __restrict__ k,
                         const float* __restrict__ v, const float* __restrict__ Wq,
                         const float* __restrict__ Wk, const float* __restrict__ Wv,
                         const float* __restrict__ Wo, unsigned short* __restrict__ dst) {
  const int bid = blockIdx.x;
  const float* src;
  int rel;
  if (bid < 24576) {
    const int seg = bid >> 13;
    rel = bid & 8191;
    src = (seg == 0) ? q : (seg == 1) ? k : v;
  } else {
    const int w = (bid - 24576) >> 10;
    rel = (bid - 24576) & 1023;
    src = (w == 0) ? Wq : (w == 1) ? Wk : (w == 2) ? Wv : Wo;
  }
  const size_t di = (size_t)bid * 1024 + threadIdx.x * 4;
  const size_t si = (size_t)rel * 1024 + threadIdx.x * 4;
  const float4 val = *(const float4*)(src + si);
  ushort4 o;
  o.x = f2bf(val.x); o.y = f2bf(val.y); o.z = f2bf(val.z); o.w = f2bf(val.w);
  *(ushort4*)(dst + di) = o;
}

// ---- fused Q/K/V^T projection GEMMs, R6 champion (BK=64, both-sides XOR
// swizzle, gload_lds both operands) + XCD chunk swizzle: gxs=(gx&7)*64+gx>>3
// gives each XCD 64 consecutive works = 8 A-panels x 8 n — A-panel fetched
// once per XCD L2, reused 8x (T1).
__global__ __launch_bounds__(256, 2)
void gemm_qkv(const unsigned short* __restrict__ xq, const unsigned short* __restrict__ xk,
              const unsigned short* __restrict__ xv, const unsigned short* __restrict__ wq,
              const unsigned short* __restrict__ wk, const unsigned short* __restrict__ wv,
              const float* __restrict__ bq, const float* __restrict__ bk,
              const float* __restrict__ bv,
              unsigned short* __restrict__ Qh, unsigned short* __restrict__ Kh,
              unsigned short* __restrict__ Vt)
{
  __shared__ __align__(16) unsigned short As[128 * 64];
  __shared__ __align__(16) unsigned short Bs[128 * 64];

  const int gy = blockIdx.y;
  const int gx = ((blockIdx.x & 7) << 6) + (blockIdx.x >> 3);   // XCD chunk swizzle (512%8==0)
  const unsigned short* A  = (gy == 0) ? xq : (gy == 1) ? xk : wv;
  const unsigned short* Bw = (gy == 0) ? wq : (gy == 1) ? wk : xv;
  const float* bias        = (gy == 0) ? bq : (gy == 1) ? bk : bv;

  int m0, n0, N;
  if (gy < 2) { m0 = (gx >> 3) * 128; n0 = (gx & 7) * 128; N = 1024; }
  else        { m0 = (gx & 7) * 128;  n0 = (gx >> 3) * 128; N = 8192; }
  const int K = 1024;

  const int tid  = threadIdx.x;
  const int wave = tid >> 6;
  const int lane = tid & 63;
  const int wm = wave >> 1, wn = wave & 1;
  const int quad = lane >> 4, l15 = lane & 15;

  f32x4 acc[4][4];
#pragma unroll
  for (int i = 0; i < 4; ++i)
#pragma unroll
    for (int j = 0; j < 4; ++j) acc[i][j] = f32x4{0.f, 0.f, 0.f, 0.f};

  // staging: 8 rows/call (lane>>3), col chunk inverse-swizzled
  const int sr8 = lane >> 3;
  const int scx = ((lane & 7) ^ (sr8 & 7)) * 8;
  const unsigned short* Agb = A  + (size_t)(m0 + wave * 8 + sr8) * K + scx;
  const unsigned short* Bgb = Bw + (size_t)(n0 + wave * 8 + sr8) * K + scx;
  unsigned short* AsW = &As[wave * 8 * 64];
  unsigned short* BsW = &Bs[wave * 8 * 64];

  // read column (per-l15 XOR unwinds the staging swizzle)
  const int colx0 = (quad * 8) ^ ((l15 & 7) * 8);
  const int colx1 = (32 + quad * 8) ^ ((l15 & 7) * 8);

  for (int k0 = 0; k0 < K; k0 += 64) {
#pragma unroll
    for (int t = 0; t < 4; ++t) {
      lds_load16(Agb + (size_t)(t * 32) * K + k0, AsW + t * 32 * 64);
      lds_load16(Bgb + (size_t)(t * 32) * K + k0, BsW + t * 32 * 64);
    }
    __syncthreads();

#pragma unroll
    for (int kd = 0; kd < 2; ++kd) {
      const int colx = kd ? colx1 : colx0;
      bf16x8 af[4], bfr[4];
#pragma unroll
      for (int i = 0; i < 4; ++i)
        af[i] = *(const bf16x8*)&As[(wm * 64 + i * 16 + l15) * 64 + colx];
#pragma unroll
      for (int j = 0; j < 4; ++j)
        bfr[j] = *(const bf16x8*)&Bs[(wn * 64 + j * 16 + l15) * 64 + colx];
#pragma unroll
      for (int i = 0; i < 4; ++i)
#pragma unroll
        for (int j = 0; j < 4; ++j)
          acc[i][j] = __builtin_amdgcn_mfma_f32_16x16x32_bf16(af[i], bfr[j], acc[i][j], 0, 0, 0);
    }
    __syncthreads();
  }

  if (gy < 2) {
    unsigned short* out = (gy == 0) ? Qh : Kh;
    const float scl = (gy == 0) ? QK_SCALE : 1.0f;
    float bj[4];
#pragma unroll
    for (int j = 0; j < 4; ++j) bj[j] = bias[n0 + wn * 64 + j * 16 + l15];
#pragma unroll
    for (int i = 0; i < 4; ++i) {
      const int mbase = m0 + wm * 64 + i * 16 + quad * 4;
#pragma unroll
      for (int j = 0; j < 4; ++j) {
        const int n = n0 + wn * 64 + j * 16 + l15;
#pragma unroll
        for (int r = 0; r < 4; ++r) {
          const int m = mbase + r;
          const float vv = (acc[i][j][r] + bj[j]) * scl;
          const size_t idx = ((((size_t)(m >> 11) * 16 + (n >> 6)) << 11) + (size_t)(m & 2047)) * 64 + (n & 63);
          out[idx] = f2bf(vv);
        }
      }
    }
  } else {
#pragma unroll
    for (int i = 0; i < 4; ++i) {
      const int mbase = m0 + wm * 64 + i * 16 + quad * 4;
      float bm[4];
#pragma unroll
      for (int r = 0; r < 4; ++r) bm[r] = bias[mbase + r];
#pragma unroll
      for (int j = 0; j < 4; ++j) {
        const int n = n0 + wn * 64 + j * 16 + l15;
#pragma unroll
        for (int r = 0; r < 4; ++r)
          Vt[(size_t)(mbase + r) * N + n] = f2bf(acc[i][j][r] + bm[r]);
      }
    }
  }
}

// ---- flash attention: R6's v7 verbatim (max-free softmax, MFMA row-sum,
// XCD swizzle, setprio) — best measured variant (111.8 us).
__global__ __launch_bounds__(256, 2)
void flash_attn(const unsigned short* __restrict__ Qh,
                const unsigned short* __restrict__ Kh,
                const unsigned short* __restrict__ VtG,
                unsigned short* __restrict__ Xo)
{
  __shared__ __align__(16) unsigned short Ks[128 * 72];   // [k][d] pad 8; also initial Q staging
  __shared__ __align__(16) unsigned short Vs[64 * 136];   // [d][k] pad 8

  // XCD swizzle: 16 q-blocks sharing one (b,h)'s K/V land on one XCD.
  const int fid = blockIdx.x + (blockIdx.y << 4) + (blockIdx.z << 8);
  const int wid = ((fid & 7) << 7) + (fid >> 3);       // bijective, 1024 % 8 == 0
  const int qb = wid & 15, h = (wid >> 4) & 15, b = wid >> 8;

  const int tid = threadIdx.x, wave = tid >> 6, lane = tid & 63;
  const int quad = lane >> 4, l15 = lane & 15;

  const size_t bh = (((size_t)b * 16 + h) << 17);          // * S*DK
  const unsigned short* Qg = Qh + bh + ((size_t)qb << 13); // * 128*64
  const unsigned short* Kg = Kh + bh;
  const unsigned short* Vg = VtG + ((size_t)(h * 64)) * 8192 + (size_t)b * 2048;

  // ---- stage Q tile into Ks region (row stride 72), read frags, done with it
#pragma unroll
  for (int p = 0; p < 4; ++p) {
    const int c = tid + p * 256;                 // 16B chunk id, 0..1023
    u16x8 qv = *(const u16x8*)(Qg + c * 8);
    *(u16x8*)&Ks[(c >> 3) * 72 + (c & 7) * 8] = qv;
  }
  __syncthreads();
  bf16x8 aq[2][2];
#pragma unroll
  for (int i = 0; i < 2; ++i)
#pragma unroll
    for (int d = 0; d < 2; ++d)
      aq[i][d] = *(const bf16x8*)&Ks[(wave * 32 + i * 16 + l15) * 72 + d * 32 + quad * 8];

  f32x4 oacc[2][4];
  f32x4 lacc[2];
#pragma unroll
  for (int i = 0; i < 2; ++i) {
#pragma unroll
    for (int jd = 0; jd < 4; ++jd) oacc[i][jd] = f32x4{0.f, 0.f, 0.f, 0.f};
    lacc[i] = f32x4{0.f, 0.f, 0.f, 0.f};
  }

  // constant all-ones bf16 B-fragment for the row-sum MFMA
  const uint32_t one2 = 0x3F803F80u;
  const u32x4 onesU{one2, one2, one2, one2};
  const bf16x8 onesB = __builtin_bit_cast(bf16x8, onesU);

  // pi5(rho(l15)): LDS base row for the permuted A-row read
  const int rb = (l15 >> 3) * 16 + ((l15 >> 2) & 1) * 4 + (l15 & 3);

  // software-pipelined K/V tile loads (prologue)
  u16x8 kreg[4], vreg[4];
#pragma unroll
  for (int p = 0; p < 4; ++p) {
    const int c = tid + p * 256;
    kreg[p] = *(const u16x8*)(Kg + c * 8);
    vreg[p] = *(const u16x8*)(Vg + (size_t)(c >> 4) * 8192 + (c & 15) * 8);
  }

  for (int kb = 0; kb < 16; ++kb) {
    __syncthreads();   // all waves done reading previous Ks/Vs (and Q staging at kb=0)
#pragma unroll
    for (int p = 0; p < 4; ++p) {
      const int c = tid + p * 256;
      const int kr = c >> 3;
      const int krp = (kr & ~12) | ((kr & 4) << 1) | ((kr & 8) >> 1);  // pi5: swap bits 2,3
      *(u16x8*)&Ks[krp * 72 + (c & 7) * 8] = kreg[p];
      *(u16x8*)&Vs[(c >> 4) * 136 + (c & 15) * 8] = vreg[p];
    }
    __syncthreads();

    // two 64-k halves; runtime loop (unroll 1) keeps per-half regs from merging
#pragma unroll 1
    for (int hh = 0; hh < 2; ++hh) {
      f32x4 s[2][4];
#pragma unroll
      for (int i = 0; i < 2; ++i)
#pragma unroll
        for (int j = 0; j < 4; ++j) s[i][j] = f32x4{0.f, 0.f, 0.f, 0.f};
      __builtin_amdgcn_s_setprio(1);
#pragma unroll
      for (int d = 0; d < 2; ++d)
#pragma unroll
        for (int j = 0; j < 4; ++j) {
          const int kk = j >> 1, p2 = j & 1;
          bf16x8 kf = *(const bf16x8*)&Ks[(hh * 64 + kk * 32 + p2 * 8 + rb) * 72 + d * 32 + quad * 8];
#pragma unroll
          for (int i = 0; i < 2; ++i)
            s[i][j] = __builtin_amdgcn_mfma_f32_16x16x32_bf16(kf, aq[i][d], s[i][j], 0, 0, 0);
        }
      __builtin_amdgcn_s_setprio(0);

      // max-free softmax: e = exp2(s) directly (v6 rationale)
#pragma unroll
      for (int i = 0; i < 2; ++i)
#pragma unroll
        for (int j = 0; j < 4; ++j)
#pragma unroll
          for (int r = 0; r < 4; ++r)
            s[i][j][r] = exp2f_fast(s[i][j][r]);

      // pack P -> bf16 A-frags (score regs die here)
      bf16x8 ap[2][2];
#pragma unroll
      for (int i = 0; i < 2; ++i)
#pragma unroll
        for (int kk = 0; kk < 2; ++kk)
          ap[i][kk] = pack8(s[i][2 * kk], s[i][2 * kk + 1]);

      // split prefetch: K after half 0, V after half 1 (16 regs each)
      if (kb < 15) {
        if (hh == 0) {
          const size_t ko = ((size_t)(kb + 1) << 13);
#pragma unroll
          for (int p = 0; p < 4; ++p) {
            const int c = tid + p * 256;
            kreg[p] = *(const u16x8*)(Kg + ko + c * 8);
          }
        } else {
#pragma unroll
          for (int p = 0; p < 4; ++p) {
            const int c = tid + p * 256;
            vreg[p] = *(const u16x8*)(Vg + (size_t)(c >> 4) * 8192 + (kb + 1) * 128 + (c & 15) * 8);
          }
        }
      }

      // l += P x ones and O += P V on the MFMA pipe
      __builtin_amdgcn_s_setprio(1);
#pragma unroll
      for (int i = 0; i < 2; ++i)
#pragma unroll
        for (int kk = 0; kk < 2; ++kk)
          lacc[i] = __builtin_amdgcn_mfma_f32_16x16x32_bf16(ap[i][kk], onesB, lacc[i], 0, 0, 0);
#pragma unroll
      for (int kk = 0; kk < 2; ++kk) {
#pragma unroll
        for (int jd = 0; jd < 4; ++jd) {
          bf16x8 bv = *(const bf16x8*)&Vs[(jd * 16 + l15) * 136 + (hh * 2 + kk) * 32 + quad * 8];
#pragma unroll
          for (int i = 0; i < 2; ++i)
            oacc[i][jd] = __builtin_amdgcn_mfma_f32_16x16x32_bf16(ap[i][kk], bv, oacc[i][jd], 0, 0, 0);
        }
      }
      __builtin_amdgcn_s_setprio(0);
    }
  }

  // epilogue: O / l, store bf16 to [B,S,H*DK]; lacc rows == oacc rows.
#pragma unroll
  for (int i = 0; i < 2; ++i)
#pragma unroll
    for (int r = 0; r < 4; ++r) {
      const float inv = 1.f / lacc[i][r];
      const int srow = qb * 128 + wave * 32 + i * 16 + quad * 4 + r;
      const size_t obase = (((size_t)b << 11) + srow) * 1024 + (h << 6);
#pragma unroll
      for (int jd = 0; jd < 4; ++jd)
        Xo[obase + jd * 16 + l15] = f2bf(oacc[i][jd][r] * inv);
    }
}

// ---- output projection: R6's BK=64 XOR-swizzle version + XCD chunk swizzle
// on the fused (bx,by) index: 8 consecutive works share an A-panel -> put
// them on one XCD (T1).
__global__ __launch_bounds__(256, 2)
void gemm_out(const unsigned short* __restrict__ A,
              const unsigned short* __restrict__ Bw,
              const float* __restrict__ bias,
              float* __restrict__ Cout)
{
  __shared__ __align__(16) unsigned short As[128 * 64];
  __shared__ __align__(16) unsigned short Bs[128 * 64];

  const int tid  = threadIdx.x;
  const int wave = tid >> 6;
  const int lane = tid & 63;
  const int wm = wave >> 1, wn = wave & 1;
  const int quad = lane >> 4, l15 = lane & 15;

  const int fid  = blockIdx.x + (blockIdx.y << 3);            // 512 blocks
  const int fids = ((fid & 7) << 6) + (fid >> 3);             // XCD chunk swizzle
  const int m0 = (fids >> 3) * 128;
  const int n0 = (fids & 7) * 128;
  const int K = 1024, N = 1024;

  f32x4 acc[4][4];
#pragma unroll
  for (int i = 0; i < 4; ++i)
#pragma unroll
    for (int j = 0; j < 4; ++j) acc[i][j] = f32x4{0.f, 0.f, 0.f, 0.f};

  const int sr8 = lane >> 3;
  const int scx = ((lane & 7) ^ (sr8 & 7)) * 8;
  const unsigned short* Agb = A  + (size_t)(m0 + wave * 8 + sr8) * K + scx;
  const unsigned short* Bgb = Bw + (size_t)(n0 + wave * 8 + sr8) * K + scx;
  unsigned short* AsW = &As[wave * 8 * 64];
  unsigned short* BsW = &Bs[wave * 8 * 64];

  const int colx0 = (quad * 8) ^ ((l15 & 7) * 8);
  const int colx1 = (32 + quad * 8) ^ ((l15 & 7) * 8);

  for (int k0 = 0; k0 < K; k0 += 64) {
#pragma unroll
    for (int t = 0; t < 4; ++t) {
      lds_load16(Agb + (size_t)(t * 32) * K + k0, AsW + t * 32 * 64);
      lds_load16(Bgb + (size_t)(t * 32) * K + k0, BsW + t * 32 * 64);
    }
    __syncthreads();

#pragma unroll
    for (int kd = 0; kd < 2; ++kd) {
      const int colx = kd ? colx1 : colx0;
      bf16x8 af[4], bfr[4];
#pragma unroll
      for (int i = 0; i < 4; ++i)
        af[i] = *(const bf16x8*)&As[(wm * 64 + i * 16 + l15) * 64 + colx];
#pragma unroll
      for (int j = 0; j < 4; ++j)
        bfr[j] = *(const bf16x8*)&Bs[(wn * 64 + j * 16 + l15) * 64 + colx];
#pragma unroll
      for (int i = 0; i < 4; ++i)
#pragma unroll
        for (int j = 0; j < 4; ++j)
          acc[i][j] = __builtin_amdgcn_mfma_f32_16x16x32_bf16(af[i], bfr[j], acc[i][j], 0, 0, 0);
    }
    __syncthreads();
  }

  float bj[4];
#pragma unroll
  for (int j = 0; j < 4; ++j) bj[j] = bias[n0 + wn * 64 + j * 16 + l15];

#pragma unroll
  for (int i = 0; i < 4; ++i) {
    const int mbase = m0 + wm * 64 + i * 16 + quad * 4;
#pragma unroll
    for (int j = 0; j < 4; ++j) {
      const int n = n0 + wn * 64 + j * 16 + l15;
#pragma unroll
      for (int r = 0; r < 4; ++r)
        Cout[(size_t)(mbase + r) * N + n] = acc[i][j][r] + bj[j];
    }
  }
}

extern "C" void kernel_launch(void* const* d_in, const int* in_sizes, int n_in,
                              void* d_out, int out_size, void* d_ws, size_t ws_size,
                              hipStream_t stream) {
  const float* q  = (const float*)d_in[0];
  const float* k  = (const float*)d_in[1];
  const float* v  = (const float*)d_in[2];
  const float* Wq = (const float*)d_in[3];
  const float* bq = (const float*)d_in[4];
  const float* Wk = (const float*)d_in[5];
  const float* bk = (const float*)d_in[6];
  const float* Wv = (const float*)d_in[7];
  const float* bv = (const float*)d_in[8];
  const float* Wo = (const float*)d_in[9];
  const float* bo = (const float*)d_in[10];

  const int B = 4, S = 2048, D = 1024, H = 16;
  const size_t NX = (size_t)B * S * D;   // 8388608
  const size_t NW = (size_t)D * D;       // 1048576

  unsigned short* xq = (unsigned short*)d_ws;
  unsigned short* xk = xq + NX;
  unsigned short* xv = xk + NX;
  unsigned short* wq = xv + NX;
  unsigned short* wk = wq + NW;
  unsigned short* wv = wk + NW;
  unsigned short* wo = wv + NW;
  unsigned short* Qh = wo + NW;   // [B,H,S,DK]
  unsigned short* Kh = Qh + NX;   // [B,H,S,DK]
  unsigned short* Vt = Kh + NX;   // [D][B*S] = V^T
  unsigned short* xo = Vt + NX;   // [B,S,D] attention output, bf16

  cast_all<<<28672, 256, 0, stream>>>(q, k, v, Wq, Wk, Wv, Wo, xq);
  gemm_qkv<<<dim3(512, 3), 256, 0, stream>>>(xq, xk, xv, wq, wk, wv, bq, bk, bv, Qh, Kh, Vt);
  flash_attn<<<dim3(S / 128, H, B), 256, 0, stream>>>(Qh, Kh, Vt, xo);
  gemm_out<<<dim3(D / 128, (B * S) / 128), 256, 0, stream>>>(xo, wo, bo, (float*)d_out);
}